// Round 1
// baseline (41.693 us; speedup 1.0000x reference)
//
#include <hip/hip_runtime.h>
#include <hip/hip_bf16.h>

#define Nn 8192
#define Mm 1024
#define Dd 1024

typedef __attribute__((ext_vector_type(8))) short short8;
typedef __attribute__((ext_vector_type(4))) short short4v;
typedef __attribute__((ext_vector_type(4))) float f32x4;

typedef const __attribute__((address_space(1))) void* gas_p;
typedef __attribute__((address_space(3))) void* las_p;

// round-to-nearest-even fp32 -> bf16 (bit pattern as short)
__device__ __forceinline__ short f2bf(float f) {
  unsigned u = __builtin_bit_cast(unsigned, f);
  u += 0x7fffu + ((u >> 16) & 1u);
  return (short)(u >> 16);
}

// ---------------- kernel 1: h (fp32) -> A (bf16) ----------------
__global__ void conv_h_kernel(const float* __restrict__ h, short* __restrict__ A) {
  long i = (long)blockIdx.x * blockDim.x + threadIdx.x; // 8 elems per thread
  const float4* h4 = (const float4*)h;
  float4 a = h4[2 * i];
  float4 b = h4[2 * i + 1];
  short8 o;
  o[0] = f2bf(a.x); o[1] = f2bf(a.y); o[2] = f2bf(a.z); o[3] = f2bf(a.w);
  o[4] = f2bf(b.x); o[5] = f2bf(b.y); o[6] = f2bf(b.z); o[7] = f2bf(b.w);
  *(short8*)(A + 8 * i) = o;
}

// ---------------- kernel 2: B'[m,d] = bf16(u*w3 + w1); c[m] = u . w2 ----------------
__global__ void prep_b_kernel(const float* __restrict__ u, const float* __restrict__ w,
                              short* __restrict__ Bp, float* __restrict__ cvec) {
  int m = blockIdx.x;      // 1024 blocks
  int t = threadIdx.x;     // 256 threads, 4 elems each
  float4 uv = ((const float4*)(u + (size_t)m * Dd))[t];
  float4 w1 = ((const float4*)(w))[t];
  float4 w2 = ((const float4*)(w + Dd))[t];
  float4 w3 = ((const float4*)(w + 2 * Dd))[t];
  float p = uv.x * w2.x + uv.y * w2.y + uv.z * w2.z + uv.w * w2.w;
  short4v o;
  o[0] = f2bf(fmaf(uv.x, w3.x, w1.x));
  o[1] = f2bf(fmaf(uv.y, w3.y, w1.y));
  o[2] = f2bf(fmaf(uv.z, w3.z, w1.z));
  o[3] = f2bf(fmaf(uv.w, w3.w, w1.w));
  *(short4v*)(Bp + (size_t)m * Dd + t * 4) = o;

  // reduce p over 256 threads (4 waves of 64)
#pragma unroll
  for (int off = 32; off > 0; off >>= 1) p += __shfl_down(p, off);
  __shared__ float sred[4];
  if ((t & 63) == 0) sred[t >> 6] = p;
  __syncthreads();
  if (t == 0) cvec[m] = sred[0] + sred[1] + sred[2] + sred[3];
}

// ---------------- kernel 3: GEMM  S = A @ B'^T + c  (m97 structure) ----------------
// 128x128 tile, BK=64, 256 threads = 4 waves (2x2), each wave 64x64 output.
// LDS layout: logical [128][64] bf16 rows, XOR-swizzled: byte ^= ((row&7)<<4).
// global_load_lds writes linearly -> inverse-swizzle the GLOBAL source chunk,
// swizzle the ds_read address (both-sides rule, m201/m173).
__global__ __launch_bounds__(256) void gemm_kernel(
    const short* __restrict__ A,   // N x D bf16
    const short* __restrict__ B,   // M x D bf16 (B')
    const float* __restrict__ cvec,// M
    float* __restrict__ out)       // N x M fp32
{
  __shared__ __align__(16) short As[128 * 64];
  __shared__ __align__(16) short Bs[128 * 64];

  const int bid = blockIdx.x;
  // bijective XCD swizzle: 512 blocks, 64 per XCD; M-dim fastest within XCD
  const int swz  = (bid & 7) * 64 + (bid >> 3);
  const int brow = swz >> 3;   // 0..63
  const int bcol = swz & 7;    // 0..7

  const int tid  = threadIdx.x;
  const int lane = tid & 63;
  const int wid  = tid >> 6;

  // --- staging: each wave stages 32 rows of A and B per K-tile (4 calls x 8 rows) ---
  // one global_load_lds(16B): 8 lanes per row, lane l -> row l/8, swizzled chunk (l%8)^(l/8)
  const int l8 = lane >> 3;
  const int kc = (lane & 7) ^ l8;          // pre-swizzled global chunk index
  const short* Ag = A + (size_t)(brow * 128 + wid * 32 + l8) * Dd + kc * 8;
  const short* Bg = B + (size_t)(bcol * 128 + wid * 32 + l8) * Dd + kc * 8;
  short* AsW = &As[(wid * 32) * 64];
  short* BsW = &Bs[(wid * 32) * 64];

  // --- fragment reads: lane l -> row (l&15), k-chunk byte (l>>4)*16, swizzle ((l&7)<<4) ---
  const int wr = wid >> 1, wc = wid & 1;
  const int arow0 = wr * 64 + (lane & 15);
  const int brow0 = wc * 64 + (lane & 15);
  const int kb = (lane >> 4) * 16;
  const int sw = (lane & 7) << 4;

  f32x4 acc[4][4] = {};

  for (int kt = 0; kt < Dd / 64; ++kt) {
    const short* Agk = Ag + kt * 64;
    const short* Bgk = Bg + kt * 64;
#pragma unroll
    for (int j = 0; j < 4; ++j) {
      __builtin_amdgcn_global_load_lds((gas_p)(Agk + j * 8 * Dd), (las_p)(AsW + j * 8 * 64), 16, 0, 0);
      __builtin_amdgcn_global_load_lds((gas_p)(Bgk + j * 8 * Dd), (las_p)(BsW + j * 8 * 64), 16, 0, 0);
    }
    __syncthreads();  // compiler emits vmcnt(0) drain -> staging visible
#pragma unroll
    for (int kk = 0; kk < 2; ++kk) {
      short8 af[4], bfr[4];
      const int koff = kk * 64 + kb;
#pragma unroll
      for (int i = 0; i < 4; ++i) {
        af[i]  = *(const short8*)((const char*)As + ((arow0 + i * 16) * 128 + (koff ^ sw)));
        bfr[i] = *(const short8*)((const char*)Bs + ((brow0 + i * 16) * 128 + (koff ^ sw)));
      }
#pragma unroll
      for (int i = 0; i < 4; ++i)
#pragma unroll
        for (int j = 0; j < 4; ++j)
          acc[i][j] = __builtin_amdgcn_mfma_f32_16x16x32_bf16(af[i], bfr[j], acc[i][j], 0, 0, 0);
    }
    __syncthreads();
  }

  // --- epilogue: S[n,m] = acc + c[m] ---
  const int n0 = brow * 128 + wr * 64 + (lane >> 4) * 4;
  const int m0 = bcol * 128 + wc * 64 + (lane & 15);
#pragma unroll
  for (int j = 0; j < 4; ++j) {
    const float cm = cvec[m0 + j * 16];
#pragma unroll
    for (int i = 0; i < 4; ++i) {
      float* op = out + (size_t)(n0 + i * 16) * Mm + m0 + j * 16;
#pragma unroll
      for (int r = 0; r < 4; ++r)
        op[(size_t)r * Mm] = acc[i][j][r] + cm;
    }
  }
}

extern "C" void kernel_launch(void* const* d_in, const int* in_sizes, int n_in,
                              void* d_out, int out_size, void* d_ws, size_t ws_size,
                              hipStream_t stream) {
  const float* h = (const float*)d_in[0];
  const float* u = (const float*)d_in[1];
  const float* w = (const float*)d_in[2];
  float* out = (float*)d_out;

  // workspace layout: A bf16 (16MB) | B' bf16 (2MB) | c fp32 (4KB)  -> ~18.9MB
  short* Abf = (short*)d_ws;
  short* Bp  = Abf + (size_t)Nn * Dd;
  float* cvec = (float*)(Bp + (size_t)Mm * Dd);

  conv_h_kernel<<<(Nn * Dd / 8) / 256, 256, 0, stream>>>(h, Abf);
  prep_b_kernel<<<Mm, 256, 0, stream>>>(u, w, Bp, cvec);
  gemm_kernel<<<(Nn / 128) * (Mm / 128), 256, 0, stream>>>(Abf, Bp, cvec, out);
}